// Round 1
// baseline (107.210 us; speedup 1.0000x reference)
//
#include <hip/hip_runtime.h>

namespace {
constexpr int kH      = 16;
constexpr int kS      = 2048;
constexpr int kD      = 64;
constexpr int kNpos   = 64;
constexpr int kHid    = 1024;   // H*D
constexpr int kChunk  = 256;    // 64 lanes * 4 elements
constexpr int kNChunks = kS / kChunk;  // 8
}

// One wave (64 lanes) per output row (h,s). 4 waves per block.
// Phase 1: logits_int[n] = dot(query[row,:], pe[h,n,:]) for n = lane.
// Phase 2: stream chunks of 256 keys right-to-left; reverse-cumsum of
//          sigmoid(attn_logits) via in-lane prefix + wave suffix scan;
//          interpolate from the 64-entry LDS logits table.
//          Early-exit once the running suffix sum >= 63 (pos clamps to 63,
//          w == 0, output == logits_int[63] for the entire remaining prefix).
__global__ __launch_bounds__(256) void cope_kernel(
    const float* __restrict__ query,
    const float* __restrict__ attn,
    const float* __restrict__ pos_emb,
    float* __restrict__ out)
{
    const int lane = threadIdx.x & 63;
    const int wid  = threadIdx.x >> 6;
    const int row  = (blockIdx.x << 2) + wid;   // row in [0, H*S)
    const int h    = row >> 11;                 // row / S

    __shared__ float lds_q[4][kD];
    __shared__ float lds_logits[4][kNpos];

    // ---- Phase 1: per-row position logits table ----
    lds_q[wid][lane] = query[(size_t)row * kD + lane];
    __syncthreads();

    const float4* perow =
        reinterpret_cast<const float4*>(pos_emb + (size_t)lane * kHid + h * kD);
    float acc = 0.0f;
    #pragma unroll
    for (int i = 0; i < kD / 4; ++i) {
        float4 p4 = perow[i];
        acc = fmaf(p4.x, lds_q[wid][4 * i + 0], acc);
        acc = fmaf(p4.y, lds_q[wid][4 * i + 1], acc);
        acc = fmaf(p4.z, lds_q[wid][4 * i + 2], acc);
        acc = fmaf(p4.w, lds_q[wid][4 * i + 3], acc);
    }
    lds_logits[wid][lane] = acc;
    __syncthreads();

    const float fill = lds_logits[wid][kNpos - 1];  // logits_int[63]

    const float* arow = attn + (size_t)row * kS;
    float*       orow = out  + (size_t)row * kS;

    // ---- Phase 2: right-to-left chunked reverse cumsum ----
    float running = 0.0f;   // sum of gates in chunks strictly right of current
    int c = kNChunks - 1;
    for (; c >= 0; --c) {
        const int base = c * kChunk + lane * 4;
        float4 x = *reinterpret_cast<const float4*>(arow + base);
        float g0 = 1.0f / (1.0f + __expf(-x.x));
        float g1 = 1.0f / (1.0f + __expf(-x.y));
        float g2 = 1.0f / (1.0f + __expf(-x.z));
        float g3 = 1.0f / (1.0f + __expf(-x.w));

        // in-lane reverse inclusive sums (element i covers g[i..3])
        float e3 = g3;
        float e2 = e3 + g2;
        float e1 = e2 + g1;
        float e0 = e1 + g0;
        const float ls = e0;  // lane total

        // wave-wide inclusive suffix scan of lane totals (Hillis-Steele)
        float s = ls;
        #pragma unroll
        for (int off = 1; off < 64; off <<= 1) {
            float t = __shfl_down(s, off);
            s += (lane + off < 64) ? t : 0.0f;
        }
        const float total = __shfl(s, 0);        // whole-chunk sum
        const float sfx   = running + (s - ls);  // exclusive suffix for this lane

        float p[4] = {sfx + e0, sfx + e1, sfx + e2, sfx + e3};
        float r[4];
        #pragma unroll
        for (int i = 0; i < 4; ++i) {
            float pc = fminf(p[i], 63.0f);
            float fl = floorf(pc);
            float w  = pc - fl;
            int  fi  = (int)fl;
            int  ci  = (w > 0.0f) ? fi + 1 : fi;   // == ceil(pc)
            float lf = lds_logits[wid][fi];
            float lc = lds_logits[wid][ci];
            r[i] = fmaf(w, lc - lf, lf);           // lc*w + lf*(1-w)
        }
        float4 o = make_float4(r[0], r[1], r[2], r[3]);
        *reinterpret_cast<float4*>(orow + base) = o;

        running += total;
        if (running >= 63.0f) break;   // everything left of chunk c clamps
    }

    // ---- Fill the clamped prefix with logits_int[63] ----
    const int fillEnd = (c > 0) ? c * kChunk : 0;  // c==-1 when loop completed
    const float4 fv = make_float4(fill, fill, fill, fill);
    for (int j = lane * 4; j < fillEnd; j += 256) {
        *reinterpret_cast<float4*>(orow + j) = fv;
    }
}

extern "C" void kernel_launch(void* const* d_in, const int* in_sizes, int n_in,
                              void* d_out, int out_size, void* d_ws, size_t ws_size,
                              hipStream_t stream) {
    const float* query   = (const float*)d_in[0];
    const float* attn    = (const float*)d_in[1];
    const float* pos_emb = (const float*)d_in[2];
    float* out = (float*)d_out;

    const int rows = kH * kS;                // 32768
    dim3 grid(rows / 4), block(256);
    cope_kernel<<<grid, block, 0, stream>>>(query, attn, pos_emb, out);
}

// Round 2
// 72.528 us; speedup vs baseline: 1.4782x; 1.4782x over previous
//
#include <hip/hip_runtime.h>

namespace {
constexpr int kH      = 16;
constexpr int kS      = 2048;
constexpr int kD      = 64;
constexpr int kNpos   = 64;
constexpr int kHid    = 1024;   // H*D
constexpr int kChunk  = 256;    // 64 lanes * 4 elements
constexpr int kNChunks = kS / kChunk;  // 8
}

// One wave (64 lanes) per output row (h,s). 4 waves per block (4 consecutive
// rows -> same h, since 4 | S).
// Phase 0: stage pe[h] (16 KB) transposed into LDS, coalesced, once per block.
// Phase 1: logits_int[n] (n = lane) = dot(q_row, pe[h][n]); q served by
//          wave-uniform scalar loads, pe by conflict-free LDS reads.
// Phase 2: stream 256-key chunks right-to-left; reverse cumsum of
//          sigmoid(attn) via in-lane sums + wave suffix scan; interpolate
//          via __shfl gather from the register-resident logits table.
//          Early-exit once running suffix sum >= 63 (pos clamps, w == 0).
__global__ __launch_bounds__(256) void cope_kernel(
    const float* __restrict__ query,
    const float* __restrict__ attn,
    const float* __restrict__ pos_emb,
    float* __restrict__ out)
{
    const int lane = threadIdx.x & 63;
    const int wid  = threadIdx.x >> 6;
    const int row  = (blockIdx.x << 2) + wid;       // row in [0, H*S)
    const int srow = __builtin_amdgcn_readfirstlane(row);  // wave-uniform
    const int h    = srow >> 11;                    // row / S

    __shared__ float pe_t[kD][kNpos + 1];           // [d][n], padded: 16.25 KB

    const float* arow = attn + (size_t)srow * kS;
    float*       orow = out  + (size_t)srow * kS;

    // Prefetch the rightmost attn chunk (every row uses it); latency hides
    // under staging + dot.
    float4 x = *reinterpret_cast<const float4*>(
        arow + (kNChunks - 1) * kChunk + lane * 4);

    // ---- Phase 0: stage pe[h] transposed (1024 float4s, 4 per thread) ----
    {
        const int t = threadIdx.x;
        #pragma unroll
        for (int k = 0; k < 4; ++k) {
            const int e  = t + 256 * k;      // float4 index in [0,1024)
            const int n  = e >> 4;           // pe row (position)
            const int d4 = (e & 15) << 2;    // d offset
            float4 p = *reinterpret_cast<const float4*>(
                pos_emb + (size_t)n * kHid + h * kD + d4);
            pe_t[d4 + 0][n] = p.x;
            pe_t[d4 + 1][n] = p.y;
            pe_t[d4 + 2][n] = p.z;
            pe_t[d4 + 3][n] = p.w;
        }
    }
    __syncthreads();

    // ---- Phase 1: logits table, lane n holds logits_int[n] in `acc` ----
    const float* qrow = query + (size_t)srow * kD;  // uniform -> s_load
    float a0 = 0.f, a1 = 0.f, a2 = 0.f, a3 = 0.f;
    #pragma unroll
    for (int d = 0; d < kD; d += 4) {
        a0 = fmaf(qrow[d + 0], pe_t[d + 0][lane], a0);
        a1 = fmaf(qrow[d + 1], pe_t[d + 1][lane], a1);
        a2 = fmaf(qrow[d + 2], pe_t[d + 2][lane], a2);
        a3 = fmaf(qrow[d + 3], pe_t[d + 3][lane], a3);
    }
    const float acc  = (a0 + a1) + (a2 + a3);
    const float fill = __shfl(acc, kNpos - 1);      // logits_int[63]

    // ---- Phase 2: right-to-left chunked reverse cumsum ----
    float running = 0.0f;   // gate sum of chunks strictly right of current
    int c = kNChunks - 1;
    for (; c >= 0; --c) {
        if (c != kNChunks - 1) {
            x = *reinterpret_cast<const float4*>(arow + c * kChunk + lane * 4);
        }
        float g0 = 1.0f / (1.0f + __expf(-x.x));
        float g1 = 1.0f / (1.0f + __expf(-x.y));
        float g2 = 1.0f / (1.0f + __expf(-x.z));
        float g3 = 1.0f / (1.0f + __expf(-x.w));

        // in-lane reverse inclusive sums (element i covers g[i..3])
        float e3 = g3;
        float e2 = e3 + g2;
        float e1 = e2 + g1;
        float e0 = e1 + g0;
        const float ls = e0;  // lane total

        // wave-wide inclusive suffix scan of lane totals
        float s = ls;
        #pragma unroll
        for (int off = 1; off < 64; off <<= 1) {
            float t = __shfl_down(s, off);
            s += (lane + off < 64) ? t : 0.0f;
        }
        const float total = __shfl(s, 0);        // whole-chunk sum
        const float sfx   = running + (s - ls);  // exclusive suffix, this lane

        float p[4] = {sfx + e0, sfx + e1, sfx + e2, sfx + e3};
        float r[4];
        #pragma unroll
        for (int i = 0; i < 4; ++i) {
            float pc = fminf(p[i], 63.0f);
            float fl = floorf(pc);
            float w  = pc - fl;
            int  fi  = (int)fl;
            int  ci  = (w > 0.0f) ? fi + 1 : fi;   // == ceil(pc)
            float lf = __shfl(acc, fi);            // logits_int[fi]
            float lc = __shfl(acc, ci);            // logits_int[ci]
            r[i] = fmaf(w, lc - lf, lf);           // lc*w + lf*(1-w)
        }
        *reinterpret_cast<float4*>(orow + c * kChunk + lane * 4) =
            make_float4(r[0], r[1], r[2], r[3]);

        running += total;
        if (running >= 63.0f) break;   // everything left of chunk c clamps
    }

    // ---- Fill the clamped prefix with logits_int[63] ----
    const int fillEnd = (c > 0) ? c * kChunk : 0;  // c==-1 when loop completed
    const float4 fv = make_float4(fill, fill, fill, fill);
    for (int j = lane * 4; j < fillEnd; j += 256) {
        *reinterpret_cast<float4*>(orow + j) = fv;
    }
}

extern "C" void kernel_launch(void* const* d_in, const int* in_sizes, int n_in,
                              void* d_out, int out_size, void* d_ws, size_t ws_size,
                              hipStream_t stream) {
    const float* query   = (const float*)d_in[0];
    const float* attn    = (const float*)d_in[1];
    const float* pos_emb = (const float*)d_in[2];
    float* out = (float*)d_out;

    const int rows = kH * kS;                // 32768
    dim3 grid(rows / 4), block(256);
    cope_kernel<<<grid, block, 0, stream>>>(query, attn, pos_emb, out);
}

// Round 3
// 68.842 us; speedup vs baseline: 1.5573x; 1.0536x over previous
//
#include <hip/hip_runtime.h>

namespace {
constexpr int kH       = 16;
constexpr int kS       = 2048;
constexpr int kD       = 64;
constexpr int kNpos    = 64;
constexpr int kHid     = 1024;  // H*D
constexpr int kChunk   = 256;   // 64 lanes * 4 floats
constexpr int kNChunks = kS / kChunk;    // 8
constexpr int kRowsPerBlock = 16;        // 4 waves * 4 rows
}

__device__ __forceinline__ float dot4f(float4 a, float qx, float qy, float qz, float qw) {
    return fmaf(a.x, qx, fmaf(a.y, qy, fmaf(a.z, qz, a.w * qw)));
}

template <int CTRL, int ROWM>
__device__ __forceinline__ float dpp_add(float v) {
    int t = __builtin_amdgcn_update_dpp(0, __float_as_int(v), CTRL, ROWM, 0xf, true);
    return v + __int_as_float(t);
}

// 64-lane inclusive prefix sum, pure VALU (classic GCN DPP scan).
__device__ __forceinline__ float wave_incl_scan(float v) {
    v = dpp_add<0x111, 0xf>(v);  // row_shr:1
    v = dpp_add<0x112, 0xf>(v);  // row_shr:2
    v = dpp_add<0x114, 0xf>(v);  // row_shr:4
    v = dpp_add<0x118, 0xf>(v);  // row_shr:8
    v = dpp_add<0x142, 0xa>(v);  // row_bcast15 -> rows 1,3
    v = dpp_add<0x143, 0xc>(v);  // row_bcast31 -> rows 2,3
    return v;
}

__device__ __forceinline__ float bcast_lane(float v, int l) {
    return __int_as_float(__builtin_amdgcn_readlane(__float_as_int(v), l));
}

// Reverse-cumsum + interpolate + store for one output row.
// acc: lane n holds logits_int[n]. x0: prefetched rightmost chunk.
__device__ __forceinline__ void process_row(const float* __restrict__ arow,
                                            float* __restrict__ orow,
                                            float acc, float4 x0, int lane) {
    const float fill = bcast_lane(acc, kNpos - 1);  // logits_int[63]
    float running = 0.0f;
    int c = kNChunks - 1;
    float4 x = x0;
    for (; c >= 0; --c) {
        if (c != kNChunks - 1)
            x = *reinterpret_cast<const float4*>(arow + c * kChunk + lane * 4);
        float g0 = 1.0f / (1.0f + __expf(-x.x));
        float g1 = 1.0f / (1.0f + __expf(-x.y));
        float g2 = 1.0f / (1.0f + __expf(-x.z));
        float g3 = 1.0f / (1.0f + __expf(-x.w));

        // in-lane reverse inclusive sums (element i covers g[i..3])
        float e3 = g3;
        float e2 = e3 + g2;
        float e1 = e2 + g1;
        float e0 = e1 + g0;          // lane total

        float incl  = wave_incl_scan(e0);        // prefix over lane totals
        float total = bcast_lane(incl, 63);
        float sfx   = running + (total - incl);  // exclusive suffix, this lane

        float p[4] = {sfx + e0, sfx + e1, sfx + e2, sfx + e3};
        float r[4];
        #pragma unroll
        for (int i = 0; i < 4; ++i) {
            float pc = fminf(p[i], 63.0f);
            float fl = floorf(pc);
            float w  = pc - fl;
            int  fi  = (int)fl;
            int  ni  = (fi < kNpos - 1) ? fi + 1 : kNpos - 1;
            float lf = __shfl(acc, fi);
            float ln = __shfl(acc, ni);
            r[i] = fmaf(w, ln - lf, lf);   // == lf when w==0 (ceil==floor case)
        }
        *reinterpret_cast<float4*>(orow + c * kChunk + lane * 4) =
            make_float4(r[0], r[1], r[2], r[3]);

        running += total;
        if (running >= 63.0f) break;   // everything left of chunk c clamps
    }
    const int fillEnd = (c > 0) ? c * kChunk : 0;
    const float4 fv = make_float4(fill, fill, fill, fill);
    for (int j = lane * 4; j < fillEnd; j += 256) {
        *reinterpret_cast<float4*>(orow + j) = fv;
    }
}

// Block = 16 consecutive rows (same head). Wave = 4 rows.
// Phase 0: stage pe[h] (16 KB) into LDS, row-major XOR-swizzled at float4
//          granularity (bank-balanced b128 access), via ds_write_b128.
// Phase 1: lane n computes logits_int[n] for 4 rows: 16 ds_read_b128 of its
//          pe row (amortized over 4 rows), q from wave-uniform scalar loads.
// Phase 2: per row: reverse cumsum of sigmoid(attn) (DPP scan), interpolate
//          via __shfl gather, early-exit + constant fill once sum >= 63.
__global__ __launch_bounds__(256) void cope_kernel(
    const float* __restrict__ query,
    const float* __restrict__ attn,
    const float* __restrict__ pos_emb,
    float* __restrict__ out)
{
    const int t    = threadIdx.x;
    const int lane = t & 63;
    const int wid  = t >> 6;
    const int row_base = blockIdx.x * kRowsPerBlock;
    const int h        = row_base >> 11;           // row / S
    const int wrow = __builtin_amdgcn_readfirstlane(row_base + wid * 4);

    __shared__ float4 pe_lds[kNpos * 16];          // 16 KB, swizzled [n][j]

    const float* arow = attn + (size_t)wrow * kS;
    float*       orow = out  + (size_t)wrow * kS;

    // Prefetch rightmost attn chunk for all 4 rows (hides under stage+dot).
    const int tail = (kNChunks - 1) * kChunk + lane * 4;
    float4 x0 = *reinterpret_cast<const float4*>(arow + 0 * kS + tail);
    float4 x1 = *reinterpret_cast<const float4*>(arow + 1 * kS + tail);
    float4 x2 = *reinterpret_cast<const float4*>(arow + 2 * kS + tail);
    float4 x3 = *reinterpret_cast<const float4*>(arow + 3 * kS + tail);

    // ---- Phase 0: stage pe[h], swizzled: slot(n,j) = n*16 + (j ^ (n&15)) ----
    #pragma unroll
    for (int k = 0; k < 4; ++k) {
        const int e = t + 256 * k;       // float4 index in [0,1024)
        const int n = e >> 4;
        const int j = e & 15;
        float4 p = *reinterpret_cast<const float4*>(
            pos_emb + (size_t)n * kHid + h * kD + 4 * j);
        pe_lds[(n << 4) | (j ^ (n & 15))] = p;
    }
    __syncthreads();

    // ---- Phase 1: 4-row dot; lane n = position n ----
    const float* qbase = query + (size_t)wrow * kD;  // uniform -> s_load
    float acc0 = 0.f, acc1 = 0.f, acc2 = 0.f, acc3 = 0.f;
    #pragma unroll 4
    for (int j = 0; j < 16; ++j) {
        float4 pe4 = pe_lds[(lane << 4) | (j ^ (lane & 15))];
        const float* q0 = qbase + 0 * kD + 4 * j;
        const float* q1 = qbase + 1 * kD + 4 * j;
        const float* q2 = qbase + 2 * kD + 4 * j;
        const float* q3 = qbase + 3 * kD + 4 * j;
        acc0 += dot4f(pe4, q0[0], q0[1], q0[2], q0[3]);
        acc1 += dot4f(pe4, q1[0], q1[1], q1[2], q1[3]);
        acc2 += dot4f(pe4, q2[0], q2[1], q2[2], q2[3]);
        acc3 += dot4f(pe4, q3[0], q3[1], q3[2], q3[3]);
    }

    // ---- Phase 2: 4 rows, unrolled (no runtime-indexed reg arrays) ----
    process_row(arow + 0 * kS, orow + 0 * kS, acc0, x0, lane);
    process_row(arow + 1 * kS, orow + 1 * kS, acc1, x1, lane);
    process_row(arow + 2 * kS, orow + 2 * kS, acc2, x2, lane);
    process_row(arow + 3 * kS, orow + 3 * kS, acc3, x3, lane);
}

extern "C" void kernel_launch(void* const* d_in, const int* in_sizes, int n_in,
                              void* d_out, int out_size, void* d_ws, size_t ws_size,
                              hipStream_t stream) {
    const float* query   = (const float*)d_in[0];
    const float* attn    = (const float*)d_in[1];
    const float* pos_emb = (const float*)d_in[2];
    float* out = (float*)d_out;

    const int rows = kH * kS;                    // 32768
    dim3 grid(rows / kRowsPerBlock), block(256); // 2048 blocks x 4 waves
    cope_kernel<<<grid, block, 0, stream>>>(query, attn, pos_emb, out);
}